// Round 13
// baseline (244.830 us; speedup 1.0000x reference)
//
#include <hip/hip_runtime.h>
#include <hip/hip_bf16.h>
#include <math.h>

// Problem dims (fixed by reference)
#define BB 64
#define SS 200
#define TT 32
#define VV 50000
#define EE 128
#define CC 128
#define HH 100
#define G3 300           // 3*H
#define OUTD 104
#define NTREE (BB*SS)    // 12800

typedef __attribute__((ext_vector_type(4))) float f32x4;
typedef _Float16 f16x8 __attribute__((ext_vector_type(8)));

#define L2E  1.4426950408889634f
#define NL2E (-1.4426950408889634f)
#define TL2E 2.8853900817779268f

// LDS-only barrier: waits ds-ops (lgkmcnt) but does NOT drain vmcnt, so in-flight
// global prefetch loads stay outstanding across the barrier (waited at use).
#define BAR() asm volatile("s_waitcnt lgkmcnt(0)\n\ts_barrier" ::: "memory")

// Workspace byte offsets (round-2 proven 34.2 MB envelope)
//   k2b  @ 32768   : 163840 B  (W_ih fragment image, fp16)
//   thi  @ 196608  : 3276800 B (tree_vec, fp16)
//   gx   @ 3473408 : 30720000 B (fp32, PRESCALED: r/z = NL2E*(x+bih+bhh), n = TL2E*(x+bih))
//   ctab @ 3473408 : 25600000 B fp32 -- ALIASES gx: k0 writes it, k1g reads it,
//                                      k2 overwrites gx only after k1g completes.
//   pool @ 0       : 51200 B  -- aliases dead wl region + k2b head; k3 writes AFTER k2.

#define LDA 136                  // fp16/row: 128 + 8 pad
#define AROWS 64

// ---------------- K0: k2b W_ih image (blocks 0-9) + ctab vocab-GEMM (blocks 10+)
// ctab[v][c] = emb[v] @ W_lin^T + b_lin  (fp32, bit-identical to the old per-node c)
__global__ __launch_bounds__(256) void k0_prep(const float* __restrict__ w_lin,
                                               const float* __restrict__ w_ih_f,
                                               const float* __restrict__ w_ih_b,
                                               const float* __restrict__ emb,
                                               const float* __restrict__ b_lin,
                                               _Float16* __restrict__ k2b,
                                               float* __restrict__ ctab) {
    __shared__ __align__(16) _Float16 A_sh[AROWS * LDA];   // 17408 B
    const int tid  = threadIdx.x;
    const int wave = tid >> 6;
    const int lane = tid & 63;
    const int r = lane & 15;
    const int q = lane >> 4;

    if (blockIdx.x < 10) {
        // k2b image: nb, wave w, lane(r,q), kt -> W_ih[padded n = nb*64+w*16+r][k=kt*32+q*8]
        const int nb = blockIdx.x;               // 0..9
        const int n = nb * 64 + wave * 16 + r;
        const int dir = (n >= 320) ? 1 : 0;
        const int j = n - dir * 320;
        const int jj = (j < G3) ? j : 0;         // pad rows clamped (results discarded)
        const float* w = dir ? w_ih_b : w_ih_f;
#pragma unroll
        for (int kt = 0; kt < 4; ++kt) {
            const float* src = w + (long)jj * EE + kt * 32 + q * 8;
            f16x8 f;
#pragma unroll
            for (int e = 0; e < 8; ++e) f[e] = (_Float16)src[e];
            *(f16x8*)&k2b[(size_t)((((nb * 4 + wave) * 4 + kt) * 64) + lane) * 8] = f;
        }
        return;
    }

    // ---- ctab pass: 64 vocab rows per block
    const int row0 = (blockIdx.x - 10) * 64;

    // W_lin B fragments built directly from global (no intra-kernel image dependency)
    f16x8 bfrag[2][4];
    float bias[2];
#pragma unroll
    for (int nt = 0; nt < 2; ++nt) {
        const int n = wave * 32 + nt * 16 + r;
        bias[nt] = b_lin[n];
#pragma unroll
        for (int kt = 0; kt < 4; ++kt) {
            const float* src = w_lin + (long)n * EE + kt * 32 + q * 8;
            f16x8 f;
#pragma unroll
            for (int e = 0; e < 8; ++e) f[e] = (_Float16)src[e];
            bfrag[nt][kt] = f;
        }
    }

    // stage 64 emb rows (fp32 -> fp16), OOB rows clamped (outputs discarded)
#pragma unroll
    for (int i = 0; i < 8; ++i) {
        const int idx = tid + i * 256;       // 0..2047
        const int row = idx >> 5;            // 64 rows, 32 float4 each
        const int p   = idx & 31;
        const int gr  = row0 + row;
        const int grc = (gr < VV) ? gr : (VV - 1);
        const float4 e = ((const float4*)(emb + (long)grc * EE))[p];
        _Float16* dst = &A_sh[row * LDA + p * 4];
        dst[0] = (_Float16)e.x; dst[1] = (_Float16)e.y;
        dst[2] = (_Float16)e.z; dst[3] = (_Float16)e.w;
    }
    __syncthreads();

    f32x4 acc[4][2];
#pragma unroll
    for (int mt = 0; mt < 4; ++mt)
#pragma unroll
        for (int nt = 0; nt < 2; ++nt) acc[mt][nt] = (f32x4)(0.f);

#pragma unroll
    for (int mt = 0; mt < 4; ++mt) {
        const int m = mt * 16 + r;
        f16x8 afrag[4];
#pragma unroll
        for (int kt = 0; kt < 4; ++kt)
            afrag[kt] = *(const f16x8*)&A_sh[m * LDA + kt * 32 + q * 8];
#pragma unroll
        for (int nt = 0; nt < 2; ++nt)
#pragma unroll
            for (int kt = 0; kt < 4; ++kt)
                acc[mt][nt] = __builtin_amdgcn_mfma_f32_16x16x32_f16(
                    afrag[kt], bfrag[nt][kt], acc[mt][nt], 0, 0, 0);
    }

#pragma unroll
    for (int mt = 0; mt < 4; ++mt)
#pragma unroll
        for (int nt = 0; nt < 2; ++nt) {
            const int col = wave * 32 + nt * 16 + r;
#pragma unroll
            for (int reg = 0; reg < 4; ++reg) {
                const int gr = row0 + mt * 16 + q * 4 + reg;
                if (gr < VV)
                    ctab[(long)gr * CC + col] = acc[mt][nt][reg] + bias[nt];
            }
        }
}

// ---------------- K1g: gather ctab rows -> in-register tree-sum -> maxpool -> thi
// Replaces the per-node GEMM (13.4 GFLOP -> 0): pure gather + VALU. No MFMA, no
// A-staging, no mid-kernel barriers. 6400 blocks, 32 independent coalesced fp32
// loads per thread (deep MLP), sum order IDENTICAL to the old C_sh path.
__global__ __launch_bounds__(256) void k1_gather(const int* __restrict__ tok,
                                                 const float* __restrict__ ctab,
                                                 _Float16* __restrict__ thi) {
    __shared__ int tok_sh[64];
    const int tid = threadIdx.x;
    const int tree0 = blockIdx.x * 2;
    if (tid < 64) tok_sh[tid] = tok[tree0 * TT + tid];
    __syncthreads();

    const int t = tid >> 7;              // tree within block
    const int j = tid & 127;             // channel
    const int* tk = &tok_sh[t * TT];

    float v[TT];
#pragma unroll
    for (int n = 0; n < TT; ++n)
        v[n] = ctab[(long)tk[n] * CC + j];

    float mx = -1e30f;
#pragma unroll
    for (int n = TT - 1; n >= 1; --n) {
        mx = fmaxf(mx, v[n]);
        v[(n - 1) >> 1] += v[n];
    }
    mx = fmaxf(mx, v[0]);
    thi[(size_t)(tree0 + t) * CC + j] = (_Float16)mx;   // fp32 sums, one fp16 round
}

// ---------------- K2 (round-10 proven): gx = X @ W_ih^T, PRESCALED.
// 4x work per block: 2 m-tiles (64 rows) x 2 nb-groups (nb, nb+5) -> 1000 blocks.
//   n<200 (gates r,z): gx = NL2E*(acc + b_ih[n] + b_hh[n])
//   n>=200 (gate n)  : gx = TL2E*(acc + b_ih[n])
__global__ __launch_bounds__(256) void k2_mfma(const _Float16* __restrict__ thi,
                                               const _Float16* __restrict__ k2b,
                                               const float* __restrict__ b_ih_f,
                                               const float* __restrict__ b_ih_b,
                                               const float* __restrict__ b_hh_f,
                                               const float* __restrict__ b_hh_b,
                                               float* __restrict__ gx) {
    __shared__ __align__(16) _Float16 Ah[64 * LDA];   // 17408 B

    const int tid  = threadIdx.x;
    const int wave = tid >> 6;
    const int lane = tid & 63;
    const int r = lane & 15;
    const int q = lane >> 4;

    const int nbp = blockIdx.x % 5;          // nb pair: {nbp, nbp+5}
    const int mb2 = blockIdx.x / 5;          // 0..199, 64 rows each
    const int m0 = mb2 * 64;

    // stage A: 64 rows x 128 fp16 = 1024 f16x8; 4 per thread (copy, no conversion)
#pragma unroll
    for (int i = 0; i < 4; ++i) {
        const int idx = tid + i * 256;
        const int row = idx >> 4;
        const int p   = idx & 15;
        f16x8 v = *(const f16x8*)&thi[(size_t)(m0 + row) * CC + p * 8];
        *(f16x8*)&Ah[row * LDA + p * 8] = v;
    }
    // B fragments for both nb groups: 8 coalesced 16B loads
    f16x8 bh[2][4];
#pragma unroll
    for (int i = 0; i < 2; ++i) {
        const int nb = nbp + i * 5;
#pragma unroll
        for (int kt = 0; kt < 4; ++kt)
            bh[i][kt] = *(const f16x8*)&k2b[(size_t)((((nb * 4 + wave) * 4 + kt) * 64) + lane) * 8];
    }
    __syncthreads();

    f32x4 acc[2][4];
#pragma unroll
    for (int i = 0; i < 2; ++i)
#pragma unroll
        for (int mt = 0; mt < 4; ++mt) acc[i][mt] = (f32x4)(0.f);

#pragma unroll
    for (int mt = 0; mt < 4; ++mt) {
        const int m = mt * 16 + r;
        f16x8 a[4];
#pragma unroll
        for (int kt = 0; kt < 4; ++kt)
            a[kt] = *(const f16x8*)&Ah[m * LDA + kt * 32 + q * 8];
#pragma unroll
        for (int i = 0; i < 2; ++i)
#pragma unroll
            for (int kt = 0; kt < 4; ++kt)
                acc[i][mt] = __builtin_amdgcn_mfma_f32_16x16x32_f16(a[kt], bh[i][kt], acc[i][mt], 0, 0, 0);
    }

#pragma unroll
    for (int i = 0; i < 2; ++i) {
        const int ng  = (nbp + i * 5) * 64 + wave * 16 + r;
        const int dir = (ng >= 320) ? 1 : 0;
        const int j   = ng - dir * 320;
        const bool valid = (j < G3);
        const float* b_ih = dir ? b_ih_b : b_ih_f;
        const float* b_hh = dir ? b_hh_b : b_hh_f;
        const float bias = valid ? b_ih[j] : 0.f;
        const float bh2  = (valid && j < 2 * HH) ? b_hh[j] : 0.f;
        const float sc   = (j < 2 * HH) ? NL2E : TL2E;
        float* gxd = gx + (long)dir * NTREE * G3;
        if (valid) {
#pragma unroll
            for (int mt = 0; mt < 4; ++mt)
#pragma unroll
                for (int reg = 0; reg < 4; ++reg) {
                    const int m = m0 + mt * 16 + q * 4 + reg;
                    gxd[(long)m * G3 + j] = sc * (acc[i][mt][reg] + bias + bh2);
                }
        }
    }
}

// ---------------- K3 v13 (FROZEN at structural floor, 87.5-88.5 us measured):
// v7 structure (4-wave chain, 4-deep RAW named prefetch, one lgkm-barrier/step)
// + prescaled gx/W_hh. Nine structural variants bracket this at >=88 us.
__global__ __launch_bounds__(256, 1) void k3_gru(const float* __restrict__ gx,
                                                 const float* __restrict__ w_hh_f,
                                                 const float* __restrict__ b_hh_f,
                                                 const float* __restrict__ w_hh_b,
                                                 const float* __restrict__ b_hh_b,
                                                 float* __restrict__ pool) {
    const int bid = blockIdx.x;   // 0..127
    const int dir = bid & 1;
    const int b = bid >> 1;
    const float* w_hh = dir ? w_hh_b : w_hh_f;
    const float* b_hh = dir ? b_hh_b : b_hh_f;

    __shared__ __align__(16) _Float16 h_sh[2][128];

    const int tid  = threadIdx.x;
    const int wave = tid >> 6;
    const int lane = tid & 63;
    const int r = lane & 15;
    const int q = lane >> 4;

    // W_hh fragments, row-permuted AND prescaled: tile i, lane r -> l=i*16+r;
    // gate=l/25, ch=l-25*gate; row = gate*H + wave*25 + ch (l>=75 zero-padded);
    // gates r,z scaled by -log2(e), gate n by +2*log2(e).
    f16x8 bf[5][4];
#pragma unroll
    for (int i = 0; i < 5; ++i) {
        const int l = i * 16 + r;
        const int gate = l / 25;
        const int ch   = l - gate * 25;
        const bool nv  = (l < 75);
        const int row  = gate * HH + wave * 25 + ch;
        const float sc = (gate == 2) ? TL2E : NL2E;
#pragma unroll
        for (int kt = 0; kt < 4; ++kt) {
            f16x8 f;
#pragma unroll
            for (int e = 0; e < 8; ++e) {
                const int k = kt * 32 + q * 8 + e;
                f[e] = (_Float16)((nv && k < HH) ? sc * w_hh[row * HH + k] : 0.f);
            }
            bf[i][kt] = f;
        }
    }

    const int m = lane;
    const int c = wave * 25 + m;
    const bool act = (m < 25);
    // only the n-gate hidden bias stays in-kernel (r/z hidden biases folded in gx)
    const float bnc = act ? TL2E * b_hh[2 * HH + c] : 0.f;

    // bpermute source lanes: V1 at lane l holds gh[l] (l<64); g4 at lane r holds gh[64+r]
    const int a_z  = (25 + m) & 63;          // row 25+m
    const int a_n1 = (50 + m) & 63;          // row 50+m if < 64
    const int a_n2 = (50 + m - 64) & 63;     // row 50+m if >= 64 (from g4)
    const bool nV1 = (50 + m) < 64;

    if (tid < 128) { h_sh[0][tid] = (_Float16)0.f; h_sh[1][tid] = (_Float16)0.f; }

    const int sstep = dir ? -1 : 1;
    const int s0 = dir ? (SS - 1) : 0;
    // lane-local base pointer into this chain's gx rows (valid for act lanes)
    const float* gp = gx + (long)dir * NTREE * G3 + (long)b * SS * G3 + c;

    // 4-deep prefetch, NAMED buffers, RAW loads only
    float pxr[4], pxz[4], pxn[4];
    if (act) {
#pragma unroll
        for (int j = 0; j < 4; ++j) {
            const long off = (long)(s0 + j * sstep) * G3;
            pxr[j] = gp[off]; pxz[j] = gp[off + HH]; pxn[j] = gp[off + 2 * HH];
        }
    }
    float hj = 0.f, hmax = -1e30f;
    __syncthreads();

    int s = s0;
    for (int t = 0; t < SS; t += 4) {
#pragma unroll
        for (int j = 0; j < 4; ++j) {
            const int p = j & 1;             // (t+j)&1, t multiple of 4

            f16x8 a[4];
#pragma unroll
            for (int kt = 0; kt < 4; ++kt)
                a[kt] = *(const f16x8*)&h_sh[p][kt * 32 + q * 8];

            // split-K: two parallel depth-2 chains per tile
            f32x4 accA[5], accB[5];
#pragma unroll
            for (int i = 0; i < 5; ++i) {
                accA[i] = (f32x4)(0.f);
                accB[i] = (f32x4)(0.f);
                accA[i] = __builtin_amdgcn_mfma_f32_16x16x32_f16(a[0], bf[i][0], accA[i], 0, 0, 0);
                accB[i] = __builtin_amdgcn_mfma_f32_16x16x32_f16(a[2], bf[i][2], accB[i], 0, 0, 0);
                accA[i] = __builtin_amdgcn_mfma_f32_16x16x32_f16(a[1], bf[i][1], accA[i], 0, 0, 0);
                accB[i] = __builtin_amdgcn_mfma_f32_16x16x32_f16(a[3], bf[i][3], accB[i], 0, 0, 0);
            }
            const float g0 = accA[0][0] + accB[0][0];
            const float g1 = accA[1][0] + accB[1][0];
            const float g2 = accA[2][0] + accB[2][0];
            const float g3 = accA[3][0] + accB[3][0];
            const float g4 = accA[4][0] + accB[4][0];
            // V1 at lane l = gh[row l] (rows 0..63); g4 at lane r = gh[64+r] (rows 64..74)
            float V1 = g0;
            V1 = (q == 1) ? g1 : V1;
            V1 = (q == 2) ? g2 : V1;
            V1 = (q == 3) ? g3 : V1;
            const float ghr = V1;                    // row m == own lane
            const float ghz = __shfl(V1, a_z);       // row 25+m
            const float vnA = __shfl(V1, a_n1);
            const float vnB = __shfl(g4, a_n2);
            const float ghn = nV1 ? vnA : vnB;       // row 50+m

            if (act) {
                // all exp2 args prebuilt: rg = sigmoid, via rcp(1+exp2(·))
                const float rg = __builtin_amdgcn_rcpf(1.f + __builtin_amdgcn_exp2f(pxr[j] + ghr));
                const float zg = __builtin_amdgcn_rcpf(1.f + __builtin_amdgcn_exp2f(pxz[j] + ghz));
                const float t1 = ghn + bnc;                          // parallel with rg
                const float an = __builtin_fmaf(rg, t1, pxn[j]);
                const float u  = __builtin_amdgcn_rcpf(1.f + __builtin_amdgcn_exp2f(an));
                const float n  = __builtin_fmaf(-2.f, u, 1.f);       // tanh
                hj = __builtin_fmaf(zg, hj - n, n);                  // (1-z)n + z h
                h_sh[1 - p][c] = (_Float16)hj;                       // write ASAP
                hmax = fmaxf(hmax, hj);
                // refill slot j for step t+j+4: RAW loads, no dependent ops
                if (t + j + 4 < SS) {
                    const long off = (long)(s + (j + 4) * sstep) * G3;
                    pxr[j] = gp[off]; pxz[j] = gp[off + HH]; pxn[j] = gp[off + 2 * HH];
                }
            }
            BAR();
        }
        s += 4 * sstep;
    }
    if (act) pool[(long)b * (2 * HH) + dir * HH + c] = hmax;
}

// ---------------- K4: out[b][o] = fc_b[o] + pool[b,:] . fc_w[o,:]
__global__ __launch_bounds__(256) void k4_fc(const float* __restrict__ pool,
                                             const float* __restrict__ fc_w,
                                             const float* __restrict__ fc_b,
                                             float* __restrict__ out) {
    const int b = blockIdx.x;
    __shared__ __align__(16) float p_sh[2 * HH];
    const int t = threadIdx.x;
    if (t < 2 * HH) p_sh[t] = pool[(long)b * (2 * HH) + t];
    __syncthreads();
    if (t < OUTD) {
        const float4* wr4 = (const float4*)(fc_w + (long)t * (2 * HH));
        const float4* p4 = (const float4*)p_sh;
        float a0 = 0.f, a1 = 0.f;
#pragma unroll
        for (int k = 0; k < 50; k += 2) {
            float4 w0 = wr4[k],   p0 = p4[k];
            float4 w1 = wr4[k+1], p1 = p4[k+1];
            a0 += w0.x*p0.x + w0.y*p0.y + w0.z*p0.z + w0.w*p0.w;
            a1 += w1.x*p1.x + w1.y*p1.y + w1.z*p1.z + w1.w*p1.w;
        }
        out[(long)b * OUTD + t] = fc_b[t] + a0 + a1;
    }
}

extern "C" void kernel_launch(void* const* d_in, const int* in_sizes, int n_in,
                              void* d_out, int out_size, void* d_ws, size_t ws_size,
                              hipStream_t stream) {
    const int*   tok    = (const int*)d_in[0];
    const float* emb    = (const float*)d_in[4];
    const float* w_lin  = (const float*)d_in[5];
    const float* b_lin  = (const float*)d_in[6];
    const float* w_ih_f = (const float*)d_in[7];
    const float* w_hh_f = (const float*)d_in[8];
    const float* b_ih_f = (const float*)d_in[9];
    const float* b_hh_f = (const float*)d_in[10];
    const float* w_ih_b = (const float*)d_in[11];
    const float* w_hh_b = (const float*)d_in[12];
    const float* b_ih_b = (const float*)d_in[13];
    const float* b_hh_b = (const float*)d_in[14];
    const float* fc_w   = (const float*)d_in[15];
    const float* fc_b   = (const float*)d_in[16];

    char* wsb = (char*)d_ws;
    _Float16* k2b  = (_Float16*)(wsb + 32768);    // 163840 B
    _Float16* thi  = (_Float16*)(wsb + 196608);   // 3276800 B
    float*    gx   = (float*)(wsb + 3473408);     // 30720000 B (ends 34.2 MB, proven)
    float*    ctab = (float*)(wsb + 3473408);     // 25.6 MB, aliases gx (k2 after k1g)
    float*    pool = (float*)(wsb);               // aliases dead wl + k2b head
    float*    out  = (float*)d_out;

    k0_prep  <<<10 + (VV + 63) / 64, 256, 0, stream>>>(w_lin, w_ih_f, w_ih_b, emb,
                                                       b_lin, k2b, ctab);
    k1_gather<<<NTREE / 2, 256, 0, stream>>>(tok, ctab, thi);
    k2_mfma  <<<(NTREE / 64) * 5, 256, 0, stream>>>(thi, k2b, b_ih_f, b_ih_b,
                                                    b_hh_f, b_hh_b, gx);
    k3_gru   <<<2 * BB, 256, 0, stream>>>(gx, w_hh_f, b_hh_f, w_hh_b, b_hh_b, pool);
    k4_fc    <<<BB, 256, 0, stream>>>(pool, fc_w, fc_b, out);
}

// Round 14
// 229.111 us; speedup vs baseline: 1.0686x; 1.0686x over previous
//
#include <hip/hip_runtime.h>
#include <hip/hip_bf16.h>
#include <math.h>

// Problem dims (fixed by reference)
#define BB 64
#define SS 200
#define TT 32
#define VV 50000
#define EE 128
#define CC 128
#define HH 100
#define G3 300           // 3*H
#define OUTD 104
#define NTREE (BB*SS)    // 12800

typedef __attribute__((ext_vector_type(4))) float f32x4;
typedef _Float16 f16x8 __attribute__((ext_vector_type(8)));

#define L2E  1.4426950408889634f
#define NL2E (-1.4426950408889634f)
#define TL2E 2.8853900817779268f

// LDS-only barrier: waits ds-ops (lgkmcnt) but does NOT drain vmcnt, so in-flight
// global prefetch loads stay outstanding across the barrier (waited at use).
#define BAR() asm volatile("s_waitcnt lgkmcnt(0)\n\ts_barrier" ::: "memory")

// Workspace byte offsets (round-2 proven layout)
//   wl    @ 0        : 32768 B   (k1 W_lin fragment image, fp16)
//   k2b   @ 32768    : 163840 B  (k2 W_ih fragment image, fp16)
//   thi   @ 196608   : 3276800 B (tree_vec, fp16)
//   gx    @ 3473408  : 30720000 B (fp32, PRESCALED: r/z = NL2E*(x+bih+bhh), n = TL2E*(x+bih))
//   emb16 @ 3473408  : 12800000 B -- ALIASES gx: k0 writes it, k1 reads it,
//                                   k2 overwrites gx only after k1 completes.
//   pool  @ 0        : 51200 B   -- aliases wl/k2b; k3 writes it AFTER k2 read them.

// ---------------- K0: weight-fragment images + fp16 embedding image (idempotent)
__global__ __launch_bounds__(256) void k0_prep(const float* __restrict__ w_lin,
                                               const float* __restrict__ w_ih_f,
                                               const float* __restrict__ w_ih_b,
                                               const float* __restrict__ emb,
                                               _Float16* __restrict__ wl,
                                               _Float16* __restrict__ k2b,
                                               _Float16* __restrict__ emb16) {
    const int tid  = threadIdx.x;
    const int wave = tid >> 6;
    const int lane = tid & 63;
    const int r = lane & 15;
    const int q = lane >> 4;
    if (blockIdx.x == 0) {
        // k1 image: wave w, lane(r,q), nt, kt -> W_lin[n=w*32+nt*16+r][k=kt*32+q*8 ..+8]
#pragma unroll
        for (int nt = 0; nt < 2; ++nt)
#pragma unroll
            for (int kt = 0; kt < 4; ++kt) {
                const int n = wave * 32 + nt * 16 + r;
                const float* src = w_lin + (long)n * EE + kt * 32 + q * 8;
                f16x8 f;
#pragma unroll
                for (int e = 0; e < 8; ++e) f[e] = (_Float16)src[e];
                *(f16x8*)&wl[(size_t)((((wave * 2 + nt) * 4 + kt) * 64) + lane) * 8] = f;
            }
    } else if (blockIdx.x <= 10) {
        // k2 image: nb, wave w, lane(r,q), kt -> W_ih[padded n = nb*64+w*16+r][k=kt*32+q*8]
        const int nb = blockIdx.x - 1;           // 0..9
        const int n = nb * 64 + wave * 16 + r;
        const int dir = (n >= 320) ? 1 : 0;
        const int j = n - dir * 320;
        const int jj = (j < G3) ? j : 0;         // pad rows clamped (results discarded)
        const float* w = dir ? w_ih_b : w_ih_f;
#pragma unroll
        for (int kt = 0; kt < 4; ++kt) {
            const float* src = w + (long)jj * EE + kt * 32 + q * 8;
            f16x8 f;
#pragma unroll
            for (int e = 0; e < 8; ++e) f[e] = (_Float16)src[e];
            *(f16x8*)&k2b[(size_t)((((nb * 4 + wave) * 4 + kt) * 64) + lane) * 8] = f;
        }
    } else {
        // fp16 embedding image: 50000*128 = 6,400,000 elems = 3125 blocks * 2048
        const long base = (long)(blockIdx.x - 11) * 2048 + (long)tid * 8;
        if (base < (long)VV * EE) {
            const float4* s = (const float4*)(emb + base);
            const float4 v0 = s[0], v1 = s[1];
            f16x8 f;
            f[0] = (_Float16)v0.x; f[1] = (_Float16)v0.y;
            f[2] = (_Float16)v0.z; f[3] = (_Float16)v0.w;
            f[4] = (_Float16)v1.x; f[5] = (_Float16)v1.y;
            f[6] = (_Float16)v1.z; f[7] = (_Float16)v1.w;
            *(f16x8*)&emb16[base] = f;
        }
    }
}

// ---------------- K1 (fp16 MFMA): embed-gather -> GEMM -> bias -> tree-sum -> maxpool
// A_sh/C_sh UNION (A dead after afrag reads; C written after a barrier).
// LDS 51.5 -> 34.1 KB => 4 blocks/CU, +33% resident waves hiding the gather.
#define K1_TPI 2
#define AROWS (K1_TPI*TT)        // 64
#define LDA 136                  // fp16/row: 128 + 8 pad
#define LDC 132                  // fp32/row: 128 + 4 pad

__global__ __launch_bounds__(256, 4) void k1_mfma(const int* __restrict__ tok,
                                                  const _Float16* __restrict__ emb16,
                                                  const _Float16* __restrict__ wl,
                                                  const float* __restrict__ b_lin,
                                                  _Float16* __restrict__ thi) {
    __shared__ __align__(16) char U_sh[AROWS * LDC * 4];   // 33792 B union
    _Float16* A_sh = (_Float16*)U_sh;                      // 17408 B image
    float*    C_sh = (float*)U_sh;                         // 33792 B image
    __shared__ int tok_sh[AROWS];

    const int tid  = threadIdx.x;
    const int wave = tid >> 6;
    const int lane = tid & 63;
    const int r = lane & 15;
    const int q = lane >> 4;

    // ---- B fragments: 8 coalesced 16B loads from the prebuilt image (no cvt VALU)
    f16x8 bfrag[2][4];
    float bias[2];
#pragma unroll
    for (int nt = 0; nt < 2; ++nt) {
        bias[nt] = b_lin[wave * 32 + nt * 16 + r];
#pragma unroll
        for (int kt = 0; kt < 4; ++kt)
            bfrag[nt][kt] = *(const f16x8*)&wl[(size_t)((((wave * 2 + nt) * 4 + kt) * 64) + lane) * 8];
    }

    const int tree0 = blockIdx.x * K1_TPI;
    if (tid < AROWS) tok_sh[tid] = tok[tree0 * TT + tid];
    __syncthreads();

    // ---- gather fp16 embeddings -> LDS (pure 16B copies)
#pragma unroll
    for (int i = 0; i < 4; ++i) {
        const int idx = tid + i * 256;       // 0..1023
        const int row = idx >> 4;            // 64 rows
        const int p   = idx & 15;            // 16 x f16x8 = 128 elems
        const f16x8 v = *(const f16x8*)&emb16[(long)tok_sh[row] * EE + p * 8];
        *(f16x8*)&A_sh[row * LDA + p * 8] = v;
    }
    __syncthreads();

    f32x4 acc[4][2];
#pragma unroll
    for (int mt = 0; mt < 4; ++mt)
#pragma unroll
        for (int nt = 0; nt < 2; ++nt) acc[mt][nt] = (f32x4)(0.f);

#pragma unroll
    for (int mt = 0; mt < 4; ++mt) {
        const int m = mt * 16 + r;
        f16x8 afrag[4];
#pragma unroll
        for (int kt = 0; kt < 4; ++kt)
            afrag[kt] = *(const f16x8*)&A_sh[m * LDA + kt * 32 + q * 8];
#pragma unroll
        for (int nt = 0; nt < 2; ++nt)
#pragma unroll
            for (int kt = 0; kt < 4; ++kt)
                acc[mt][nt] = __builtin_amdgcn_mfma_f32_16x16x32_f16(
                    afrag[kt], bfrag[nt][kt], acc[mt][nt], 0, 0, 0);
    }
    __syncthreads();   // all waves done READING A_sh; safe to overwrite with C

#pragma unroll
    for (int mt = 0; mt < 4; ++mt)
#pragma unroll
        for (int nt = 0; nt < 2; ++nt) {
            const int col = wave * 32 + nt * 16 + r;
#pragma unroll
            for (int reg = 0; reg < 4; ++reg) {
                const int row = mt * 16 + q * 4 + reg;
                C_sh[row * LDC + col] = acc[mt][nt][reg] + bias[nt];
            }
        }
    __syncthreads();

    // ---- tree-sum + maxpool in registers (descending index = topological order)
    {
        const int t = tid >> 7;
        const int j = tid & 127;
        const float* base = &C_sh[(t * TT) * LDC + j];
        float v[TT];
#pragma unroll
        for (int n = 0; n < TT; ++n) v[n] = base[n * LDC];
        float mx = -1e30f;
#pragma unroll
        for (int n = TT - 1; n >= 1; --n) {
            mx = fmaxf(mx, v[n]);
            v[(n - 1) >> 1] += v[n];
        }
        mx = fmaxf(mx, v[0]);
        thi[(size_t)(tree0 + t) * CC + j] = (_Float16)mx;   // fp32 sums, one fp16 round
    }
}

// ---------------- K2 (fp16 MFMA): gx = X @ W_ih^T, PRESCALED (v11-validated).
// 4x work per block: 2 m-tiles (64 rows) x 2 nb-groups (nb, nb+5) -> 1000 blocks.
//   n<200 (gates r,z): gx = NL2E*(acc + b_ih[n] + b_hh[n])
//   n>=200 (gate n)  : gx = TL2E*(acc + b_ih[n])
__global__ __launch_bounds__(256) void k2_mfma(const _Float16* __restrict__ thi,
                                               const _Float16* __restrict__ k2b,
                                               const float* __restrict__ b_ih_f,
                                               const float* __restrict__ b_ih_b,
                                               const float* __restrict__ b_hh_f,
                                               const float* __restrict__ b_hh_b,
                                               float* __restrict__ gx) {
    __shared__ __align__(16) _Float16 Ah[64 * LDA];   // 17408 B

    const int tid  = threadIdx.x;
    const int wave = tid >> 6;
    const int lane = tid & 63;
    const int r = lane & 15;
    const int q = lane >> 4;

    const int nbp = blockIdx.x % 5;          // nb pair: {nbp, nbp+5}
    const int mb2 = blockIdx.x / 5;          // 0..199, 64 rows each
    const int m0 = mb2 * 64;

    // stage A: 64 rows x 128 fp16 = 1024 f16x8; 4 per thread (copy, no conversion)
#pragma unroll
    for (int i = 0; i < 4; ++i) {
        const int idx = tid + i * 256;
        const int row = idx >> 4;
        const int p   = idx & 15;
        f16x8 v = *(const f16x8*)&thi[(size_t)(m0 + row) * CC + p * 8];
        *(f16x8*)&Ah[row * LDA + p * 8] = v;
    }
    // B fragments for both nb groups: 8 coalesced 16B loads
    f16x8 bh[2][4];
#pragma unroll
    for (int i = 0; i < 2; ++i) {
        const int nb = nbp + i * 5;
#pragma unroll
        for (int kt = 0; kt < 4; ++kt)
            bh[i][kt] = *(const f16x8*)&k2b[(size_t)((((nb * 4 + wave) * 4 + kt) * 64) + lane) * 8];
    }
    __syncthreads();

    f32x4 acc[2][4];
#pragma unroll
    for (int i = 0; i < 2; ++i)
#pragma unroll
        for (int mt = 0; mt < 4; ++mt) acc[i][mt] = (f32x4)(0.f);

#pragma unroll
    for (int mt = 0; mt < 4; ++mt) {
        const int m = mt * 16 + r;
        f16x8 a[4];
#pragma unroll
        for (int kt = 0; kt < 4; ++kt)
            a[kt] = *(const f16x8*)&Ah[m * LDA + kt * 32 + q * 8];
#pragma unroll
        for (int i = 0; i < 2; ++i)
#pragma unroll
            for (int kt = 0; kt < 4; ++kt)
                acc[i][mt] = __builtin_amdgcn_mfma_f32_16x16x32_f16(a[kt], bh[i][kt], acc[i][mt], 0, 0, 0);
    }

#pragma unroll
    for (int i = 0; i < 2; ++i) {
        const int ng  = (nbp + i * 5) * 64 + wave * 16 + r;
        const int dir = (ng >= 320) ? 1 : 0;
        const int j   = ng - dir * 320;
        const bool valid = (j < G3);
        const float* b_ih = dir ? b_ih_b : b_ih_f;
        const float* b_hh = dir ? b_hh_b : b_hh_f;
        const float bias = valid ? b_ih[j] : 0.f;
        const float bh2  = (valid && j < 2 * HH) ? b_hh[j] : 0.f;
        const float sc   = (j < 2 * HH) ? NL2E : TL2E;
        float* gxd = gx + (long)dir * NTREE * G3;
        if (valid) {
#pragma unroll
            for (int mt = 0; mt < 4; ++mt)
#pragma unroll
                for (int reg = 0; reg < 4; ++reg) {
                    const int m = m0 + mt * 16 + q * 4 + reg;
                    gxd[(long)m * G3 + j] = sc * (acc[i][mt][reg] + bias + bh2);
                }
        }
    }
}

// ---------------- K3 v13 (FROZEN at structural floor, 87.5-88.5 us measured):
// v7 structure (4-wave chain, 4-deep RAW named prefetch, one lgkm-barrier/step)
// + prescaled gx/W_hh. Ten structural variants bracket this at >=88 us.
__global__ __launch_bounds__(256, 1) void k3_gru(const float* __restrict__ gx,
                                                 const float* __restrict__ w_hh_f,
                                                 const float* __restrict__ b_hh_f,
                                                 const float* __restrict__ w_hh_b,
                                                 const float* __restrict__ b_hh_b,
                                                 float* __restrict__ pool) {
    const int bid = blockIdx.x;   // 0..127
    const int dir = bid & 1;
    const int b = bid >> 1;
    const float* w_hh = dir ? w_hh_b : w_hh_f;
    const float* b_hh = dir ? b_hh_b : b_hh_f;

    __shared__ __align__(16) _Float16 h_sh[2][128];

    const int tid  = threadIdx.x;
    const int wave = tid >> 6;
    const int lane = tid & 63;
    const int r = lane & 15;
    const int q = lane >> 4;

    // W_hh fragments, row-permuted AND prescaled: tile i, lane r -> l=i*16+r;
    // gate=l/25, ch=l-25*gate; row = gate*H + wave*25 + ch (l>=75 zero-padded);
    // gates r,z scaled by -log2(e), gate n by +2*log2(e).
    f16x8 bf[5][4];
#pragma unroll
    for (int i = 0; i < 5; ++i) {
        const int l = i * 16 + r;
        const int gate = l / 25;
        const int ch   = l - gate * 25;
        const bool nv  = (l < 75);
        const int row  = gate * HH + wave * 25 + ch;
        const float sc = (gate == 2) ? TL2E : NL2E;
#pragma unroll
        for (int kt = 0; kt < 4; ++kt) {
            f16x8 f;
#pragma unroll
            for (int e = 0; e < 8; ++e) {
                const int k = kt * 32 + q * 8 + e;
                f[e] = (_Float16)((nv && k < HH) ? sc * w_hh[row * HH + k] : 0.f);
            }
            bf[i][kt] = f;
        }
    }

    const int m = lane;
    const int c = wave * 25 + m;
    const bool act = (m < 25);
    // only the n-gate hidden bias stays in-kernel (r/z hidden biases folded in gx)
    const float bnc = act ? TL2E * b_hh[2 * HH + c] : 0.f;

    // bpermute source lanes: V1 at lane l holds gh[l] (l<64); g4 at lane r holds gh[64+r]
    const int a_z  = (25 + m) & 63;          // row 25+m
    const int a_n1 = (50 + m) & 63;          // row 50+m if < 64
    const int a_n2 = (50 + m - 64) & 63;     // row 50+m if >= 64 (from g4)
    const bool nV1 = (50 + m) < 64;

    if (tid < 128) { h_sh[0][tid] = (_Float16)0.f; h_sh[1][tid] = (_Float16)0.f; }

    const int sstep = dir ? -1 : 1;
    const int s0 = dir ? (SS - 1) : 0;
    // lane-local base pointer into this chain's gx rows (valid for act lanes)
    const float* gp = gx + (long)dir * NTREE * G3 + (long)b * SS * G3 + c;

    // 4-deep prefetch, NAMED buffers, RAW loads only
    float pxr[4], pxz[4], pxn[4];
    if (act) {
#pragma unroll
        for (int j = 0; j < 4; ++j) {
            const long off = (long)(s0 + j * sstep) * G3;
            pxr[j] = gp[off]; pxz[j] = gp[off + HH]; pxn[j] = gp[off + 2 * HH];
        }
    }
    float hj = 0.f, hmax = -1e30f;
    __syncthreads();

    int s = s0;
    for (int t = 0; t < SS; t += 4) {
#pragma unroll
        for (int j = 0; j < 4; ++j) {
            const int p = j & 1;             // (t+j)&1, t multiple of 4

            f16x8 a[4];
#pragma unroll
            for (int kt = 0; kt < 4; ++kt)
                a[kt] = *(const f16x8*)&h_sh[p][kt * 32 + q * 8];

            // split-K: two parallel depth-2 chains per tile
            f32x4 accA[5], accB[5];
#pragma unroll
            for (int i = 0; i < 5; ++i) {
                accA[i] = (f32x4)(0.f);
                accB[i] = (f32x4)(0.f);
                accA[i] = __builtin_amdgcn_mfma_f32_16x16x32_f16(a[0], bf[i][0], accA[i], 0, 0, 0);
                accB[i] = __builtin_amdgcn_mfma_f32_16x16x32_f16(a[2], bf[i][2], accB[i], 0, 0, 0);
                accA[i] = __builtin_amdgcn_mfma_f32_16x16x32_f16(a[1], bf[i][1], accA[i], 0, 0, 0);
                accB[i] = __builtin_amdgcn_mfma_f32_16x16x32_f16(a[3], bf[i][3], accB[i], 0, 0, 0);
            }
            const float g0 = accA[0][0] + accB[0][0];
            const float g1 = accA[1][0] + accB[1][0];
            const float g2 = accA[2][0] + accB[2][0];
            const float g3 = accA[3][0] + accB[3][0];
            const float g4 = accA[4][0] + accB[4][0];
            // V1 at lane l = gh[row l] (rows 0..63); g4 at lane r = gh[64+r] (rows 64..74)
            float V1 = g0;
            V1 = (q == 1) ? g1 : V1;
            V1 = (q == 2) ? g2 : V1;
            V1 = (q == 3) ? g3 : V1;
            const float ghr = V1;                    // row m == own lane
            const float ghz = __shfl(V1, a_z);       // row 25+m
            const float vnA = __shfl(V1, a_n1);
            const float vnB = __shfl(g4, a_n2);
            const float ghn = nV1 ? vnA : vnB;       // row 50+m

            if (act) {
                // all exp2 args prebuilt: rg = sigmoid, via rcp(1+exp2(·))
                const float rg = __builtin_amdgcn_rcpf(1.f + __builtin_amdgcn_exp2f(pxr[j] + ghr));
                const float zg = __builtin_amdgcn_rcpf(1.f + __builtin_amdgcn_exp2f(pxz[j] + ghz));
                const float t1 = ghn + bnc;                          // parallel with rg
                const float an = __builtin_fmaf(rg, t1, pxn[j]);
                const float u  = __builtin_amdgcn_rcpf(1.f + __builtin_amdgcn_exp2f(an));
                const float n  = __builtin_fmaf(-2.f, u, 1.f);       // tanh
                hj = __builtin_fmaf(zg, hj - n, n);                  // (1-z)n + z h
                h_sh[1 - p][c] = (_Float16)hj;                       // write ASAP
                hmax = fmaxf(hmax, hj);
                // refill slot j for step t+j+4: RAW loads, no dependent ops
                if (t + j + 4 < SS) {
                    const long off = (long)(s + (j + 4) * sstep) * G3;
                    pxr[j] = gp[off]; pxz[j] = gp[off + HH]; pxn[j] = gp[off + 2 * HH];
                }
            }
            BAR();
        }
        s += 4 * sstep;
    }
    if (act) pool[(long)b * (2 * HH) + dir * HH + c] = hmax;
}

// ---------------- K4: out[b][o] = fc_b[o] + pool[b,:] . fc_w[o,:]
__global__ __launch_bounds__(256) void k4_fc(const float* __restrict__ pool,
                                             const float* __restrict__ fc_w,
                                             const float* __restrict__ fc_b,
                                             float* __restrict__ out) {
    const int b = blockIdx.x;
    __shared__ __align__(16) float p_sh[2 * HH];
    const int t = threadIdx.x;
    if (t < 2 * HH) p_sh[t] = pool[(long)b * (2 * HH) + t];
    __syncthreads();
    if (t < OUTD) {
        const float4* wr4 = (const float4*)(fc_w + (long)t * (2 * HH));
        const float4* p4 = (const float4*)p_sh;
        float a0 = 0.f, a1 = 0.f;
#pragma unroll
        for (int k = 0; k < 50; k += 2) {
            float4 w0 = wr4[k],   p0 = p4[k];
            float4 w1 = wr4[k+1], p1 = p4[k+1];
            a0 += w0.x*p0.x + w0.y*p0.y + w0.z*p0.z + w0.w*p0.w;
            a1 += w1.x*p1.x + w1.y*p1.y + w1.z*p1.z + w1.w*p1.w;
        }
        out[(long)b * OUTD + t] = fc_b[t] + a0 + a1;
    }
}

extern "C" void kernel_launch(void* const* d_in, const int* in_sizes, int n_in,
                              void* d_out, int out_size, void* d_ws, size_t ws_size,
                              hipStream_t stream) {
    const int*   tok    = (const int*)d_in[0];
    const float* emb    = (const float*)d_in[4];
    const float* w_lin  = (const float*)d_in[5];
    const float* b_lin  = (const float*)d_in[6];
    const float* w_ih_f = (const float*)d_in[7];
    const float* w_hh_f = (const float*)d_in[8];
    const float* b_ih_f = (const float*)d_in[9];
    const float* b_hh_f = (const float*)d_in[10];
    const float* w_ih_b = (const float*)d_in[11];
    const float* w_hh_b = (const float*)d_in[12];
    const float* b_ih_b = (const float*)d_in[13];
    const float* b_hh_b = (const float*)d_in[14];
    const float* fc_w   = (const float*)d_in[15];
    const float* fc_b   = (const float*)d_in[16];

    char* wsb = (char*)d_ws;
    _Float16* wl    = (_Float16*)(wsb);             // 32768 B
    _Float16* k2b   = (_Float16*)(wsb + 32768);     // 163840 B
    _Float16* thi   = (_Float16*)(wsb + 196608);    // 3276800 B
    float*    gx    = (float*)(wsb + 3473408);      // 30720000 B
    _Float16* emb16 = (_Float16*)(wsb + 3473408);   // aliases gx: k0->k1 use, k2 overwrites
    float*    pool  = (float*)(wsb);                // aliases wl/k2b: k3 runs after k2
    float*    out   = (float*)d_out;

    k0_prep<<<11 + 3125, 256, 0, stream>>>(w_lin, w_ih_f, w_ih_b, emb, wl, k2b, emb16);
    k1_mfma<<<NTREE / K1_TPI, 256, 0, stream>>>(tok, emb16, wl, b_lin, thi);
    k2_mfma<<<(NTREE / 64) * 5, 256, 0, stream>>>(thi, k2b, b_ih_f, b_ih_b,
                                                  b_hh_f, b_hh_b, gx);
    k3_gru <<<2 * BB, 256, 0, stream>>>(gx, w_hh_f, b_hh_f, w_hh_b, b_hh_b, pool);
    k4_fc  <<<BB, 256, 0, stream>>>(pool, fc_w, fc_b, out);
}